// Round 4
// baseline (424.808 us; speedup 1.0000x reference)
//
#include <hip/hip_runtime.h>
#include <hip/hip_bf16.h>

#define NFEAT 50
#define LN_EPS 1e-5f
#define NEG_INF_C (-1000000000.0f)

typedef __bf16 bf16_t;
typedef __bf16 bf16x8 __attribute__((ext_vector_type(8)));
typedef __bf16 bf16x4 __attribute__((ext_vector_type(4)));
typedef float f32x4 __attribute__((ext_vector_type(4)));

// ws layout (all produced by prep kernels):
//   bf16[0]      attnT  [2][64][64]          attnT[t][g][f] = attn[t][f][g], zero-padded
//   bf16[8192]   WT     [4][64][64]          WT[t*2+i][e][k] = w0[t][i*64+k][e]
//   byte 49152   U_sw   [2][4][2][64][8] f32 gate matrix, A-frag-swizzled:
//                  U_sw[t][mm][kc][q*16+l16][j] = U[t][f=mm*16+l16][k=kc*32+q*8+j]
//   byte 81920   constv [2] f32              c_t = sum(tb_t*gw) + gb

__device__ inline float dot4(f32x4 a, f32x4 b) {
  return a[0]*b[0] + a[1]*b[1] + a[2]*b[2] + a[3]*b[3];
}

__global__ __launch_bounds__(256) void prep_kernel(
    const float* __restrict__ masker, const float* __restrict__ ln_w,
    const float* __restrict__ ln_b, const float* __restrict__ tw,
    bf16_t* __restrict__ ws_attnT, bf16_t* __restrict__ ws_WT)
{
  const int tid = threadIdx.x;
  const int lane = tid & 63;

  // ---- WT staging: 16 blocks x 256 threads x 4 elems = 16384 ----
  const int gidx = blockIdx.x * 256 + tid;
#pragma unroll
  for (int j = 0; j < 4; ++j) {
    int o = gidx * 4 + j;            // ((t*2+i)*64 + e)*64 + k
    int k = o & 63;
    int e = (o >> 6) & 63;
    int ti = o >> 12;                // t*2+i
    ws_WT[o] = (bf16_t)tw[(ti * 64 + k) * 64 + e];
  }

  // ---- attention columns: 128 tasks (t,g) over 64 waves, 2 each ----
  const int wg = blockIdx.x * 4 + (tid >> 6);  // 0..63
  const int f = lane;
  const bool fv = (f < NFEAT);
  for (int i = 0; i < 2; ++i) {
    int col = wg * 2 + i;            // 0..127
    int t = col >> 6, g = col & 63;
    float val = 0.f;
    if (fv && g < NFEAT) {
      float a0 = masker[((t * 3 + 0) * NFEAT + f) * NFEAT + g];
      float a1 = masker[((t * 3 + 1) * NFEAT + f) * NFEAT + g];
      float a2 = masker[((t * 3 + 2) * NFEAT + f) * NFEAT + g];
      float prod = a0 * a1 * a2;
      val = prod > 0.f ? prod : 0.f;            // relu
    }
    float s = val;
    for (int off = 32; off > 0; off >>= 1) s += __shfl_xor(s, off);
    float mean = s / (float)NFEAT;
    float d = fv ? (val - mean) : 0.f;
    float v2 = d * d;
    for (int off = 32; off > 0; off >>= 1) v2 += __shfl_xor(v2, off);
    float var = v2 / (float)NFEAT;
    float lw = fv ? ln_w[f] : 0.f;
    float lb = fv ? ln_b[f] : 0.f;
    float aln = d * rsqrtf(var + LN_EPS) * lw + lb;
    float logit = aln + ((val != 0.f) ? 0.f : NEG_INF_C) + ((f == g) ? 1.f : 0.f);
    if (!fv) logit = -3.0e38f;
    float mx = logit;
    for (int off = 32; off > 0; off >>= 1) mx = fmaxf(mx, __shfl_xor(mx, off));
    float ex = fv ? expf(logit - mx) : 0.f;
    float se = ex;
    for (int off = 32; off > 0; off >>= 1) se += __shfl_xor(se, off);
    float attn = (fv && g < NFEAT && val != 0.f) ? (ex / se) : 0.f;
    ws_attnT[(t * 64 + g) * 64 + f] = (bf16_t)attn;
  }
}

// Gate precompute: U[t][f][k] = sum_e( W1_t[k,e]*gw[f,e] + W2_t[k,e]*v[t][f,e] ),
// v[t][f',e] = sum_{g<50} attnT[t][g][f']*gw[g,e];  const_t = sum(tb_t*gw) + gb.
__global__ __launch_bounds__(256) void prep2_kernel(
    const float* __restrict__ tw, const float* __restrict__ tb,
    const float* __restrict__ gw, const float* __restrict__ gb,
    const bf16_t* __restrict__ ws_attnT, float* __restrict__ ws_U,
    float* __restrict__ ws_const)
{
  __shared__ float sv[2 * 64 * 64];   // v[t][f'][e], 32 KB
  __shared__ float sred[8];
  const int tid = threadIdx.x;
  const int lane = tid & 63, w = tid >> 6;

  // phase A: v
  for (int i = 0; i < 32; ++i) {
    int idx = tid + i * 256;          // ((t*64+f')*64+e)
    int e = idx & 63, fp = (idx >> 6) & 63, t = idx >> 12;
    float s = 0.f;
    for (int g = 0; g < NFEAT; ++g)
      s += (float)ws_attnT[(t * 64 + g) * 64 + fp] * gw[g * 64 + e];
    sv[idx] = s;
  }
  // const partials (tb flat: t*3200 + f*64 + e, f<50)
  float c0 = 0.f, c1 = 0.f;
  for (int i = tid; i < 3200; i += 256) {
    c0 += tb[i] * gw[i];
    c1 += tb[3200 + i] * gw[i];
  }
  for (int off = 32; off > 0; off >>= 1) { c0 += __shfl_xor(c0, off); c1 += __shfl_xor(c1, off); }
  if (lane == 0) { sred[w * 2] = c0; sred[w * 2 + 1] = c1; }
  __syncthreads();
  if (tid == 0) {
    float g = gb[0];
    ws_const[0] = sred[0] + sred[2] + sred[4] + sred[6] + g;
    ws_const[1] = sred[1] + sred[3] + sred[5] + sred[7] + g;
  }

  // phase B: U (swizzled into A-frag layout)
  for (int i = 0; i < 32; ++i) {
    int idx = tid + i * 256;          // ((t*64+f)*64+k)
    int k = idx & 63, f = (idx >> 6) & 63, t = idx >> 12;
    float u = 0.f;
    if (f < NFEAT) {
      const float* W1 = tw + ((t * 2 + 0) * 64 + k) * 64;
      const float* W2 = tw + ((t * 2 + 1) * 64 + k) * 64;
      const float* vp = sv + (t * 64 + f) * 64;
      const float* gwp = gw + f * 64;
      for (int e = 0; e < 64; ++e)
        u += W1[e] * gwp[e] + W2[e] * vp[e];
    }
    int mm = f >> 4, l16r = f & 15, kc = k >> 5, q = (k >> 3) & 3, j = k & 7;
    ws_U[((((t * 4 + mm) * 2 + kc) * 64) + (q * 16 + l16r)) * 8 + j] = u;
  }
}

// Barrier-free main: wave = (b = blockIdx, e-slice = wave id). Each wave computes
// all 4 m-tiles for its 16 output columns; P round-trips through wave-private LDS
// (same-wave lgkmcnt only, NO __syncthreads); gate via precomputed U dot, in-wave.
__global__ __launch_bounds__(256) void main_kernel(
    const float* __restrict__ feat, const float* __restrict__ tb,
    const bf16_t* __restrict__ ws_attnT, const bf16_t* __restrict__ ws_WT,
    const float* __restrict__ ws_U, const float* __restrict__ ws_const,
    float* __restrict__ out)
{
  __shared__ bf16_t sP[4 * 2 * 16 * 72];   // [wave][t][16 e][72 f'-pitch]
  const int tid = threadIdx.x;
  const int w = tid >> 6;
  const int lane = tid & 63;
  const int l16 = lane & 15;
  const int quad = lane >> 4;
  const int e0 = w * 16;
  const int b = blockIdx.x;
  const float* featb = feat + b * (NFEAT * 64);

  // ---- F A-frags (fp32 -> bf16) + gate dot on the fly ----
  bf16x8 A[4][2];
  float g0 = 0.f, g1 = 0.f;
#pragma unroll
  for (int mm = 0; mm < 4; ++mm) {
    const int fr = mm * 16 + l16;
#pragma unroll
    for (int kc = 0; kc < 2; ++kc) {
      f32x4 x0 = {0.f, 0.f, 0.f, 0.f}, x1 = {0.f, 0.f, 0.f, 0.f};
      if (fr < NFEAT) {
        const f32x4* pa = (const f32x4*)(featb + fr * 64 + kc * 32 + quad * 8);
        x0 = pa[0]; x1 = pa[1];
      }
      const f32x4* u0 = (const f32x4*)(ws_U + ((((0 * 4 + mm) * 2 + kc) * 64) + lane) * 8);
      const f32x4* u1 = (const f32x4*)(ws_U + ((((1 * 4 + mm) * 2 + kc) * 64) + lane) * 8);
      g0 += dot4(x0, u0[0]) + dot4(x1, u0[1]);
      g1 += dot4(x0, u1[0]) + dot4(x1, u1[1]);
      bf16x8 a;
      a[0] = (bf16_t)x0[0]; a[1] = (bf16_t)x0[1]; a[2] = (bf16_t)x0[2]; a[3] = (bf16_t)x0[3];
      a[4] = (bf16_t)x1[0]; a[5] = (bf16_t)x1[1]; a[6] = (bf16_t)x1[2]; a[7] = (bf16_t)x1[3];
      A[mm][kc] = a;
    }
  }
#pragma unroll
  for (int off = 32; off > 0; off >>= 1) {
    g0 += __shfl_xor(g0, off);
    g1 += __shfl_xor(g1, off);
  }
  g0 += ws_const[0]; g1 += ws_const[1];
  const float mx = fmaxf(g0, g1);
  const float ex0 = expf(g0 - mx), ex1 = expf(g1 - mx);
  const float inv = 1.f / (ex0 + ex1);
  const float ga0 = ex0 * inv, ga1 = ex1 * inv;

  f32x4 H[2][4];
#pragma unroll
  for (int t = 0; t < 2; ++t) {
    // ---- P = F @ W2_t (this wave's e-slice, all f' rows) ----
    f32x4 P[4];
#pragma unroll
    for (int mm = 0; mm < 4; ++mm) P[mm] = (f32x4){0.f, 0.f, 0.f, 0.f};
#pragma unroll
    for (int kc = 0; kc < 2; ++kc) {
      const bf16x8 bw2 = *(const bf16x8*)(ws_WT + ((t * 2 + 1) * 64 + e0 + l16) * 64 + kc * 32 + quad * 8);
#pragma unroll
      for (int mm = 0; mm < 4; ++mm)
        P[mm] = __builtin_amdgcn_mfma_f32_16x16x32_bf16(A[mm][kc], bw2, P[mm], 0, 0, 0);
    }
    // ---- wave-private LDS transpose: sP[e][f'] (no barrier, same-wave lgkmcnt) ----
    bf16_t* sp = sP + (w * 2 + t) * (16 * 72);
#pragma unroll
    for (int mm = 0; mm < 4; ++mm) {
      bf16x4 pv;
      pv[0] = (bf16_t)P[mm][0]; pv[1] = (bf16_t)P[mm][1];
      pv[2] = (bf16_t)P[mm][2]; pv[3] = (bf16_t)P[mm][3];
      *(bf16x4*)(sp + l16 * 72 + mm * 16 + quad * 4) = pv;
    }
    // ---- H_t = F@W1_t + attnT_t@P ----
#pragma unroll
    for (int mm = 0; mm < 4; ++mm) H[t][mm] = (f32x4){0.f, 0.f, 0.f, 0.f};
#pragma unroll
    for (int kc = 0; kc < 2; ++kc) {
      const bf16x8 bw1 = *(const bf16x8*)(ws_WT + ((t * 2 + 0) * 64 + e0 + l16) * 64 + kc * 32 + quad * 8);
#pragma unroll
      for (int mm = 0; mm < 4; ++mm)
        H[t][mm] = __builtin_amdgcn_mfma_f32_16x16x32_bf16(A[mm][kc], bw1, H[t][mm], 0, 0, 0);
    }
#pragma unroll
    for (int kc = 0; kc < 2; ++kc) {
      const bf16x8 bp = *(const bf16x8*)(sp + l16 * 72 + kc * 32 + quad * 8);
#pragma unroll
      for (int mm = 0; mm < 4; ++mm) {
        const bf16x8 ac = *(const bf16x8*)(ws_attnT + (t * 64 + mm * 16 + l16) * 64 + kc * 32 + quad * 8);
        H[t][mm] = __builtin_amdgcn_mfma_f32_16x16x32_bf16(ac, bp, H[t][mm], 0, 0, 0);
      }
    }
  }

  // ---- epilogue: +tb, gate-weighted sum, store ----
  float* outb = out + b * (NFEAT * 64);
#pragma unroll
  for (int mm = 0; mm < 4; ++mm) {
#pragma unroll
    for (int r = 0; r < 4; ++r) {
      const int f = mm * 16 + quad * 4 + r;
      if (f < NFEAT) {
        const int o = f * 64 + e0 + l16;
        outb[o] = ga0 * (H[0][mm][r] + tb[o]) + ga1 * (H[1][mm][r] + tb[3200 + o]);
      }
    }
  }
}

extern "C" void kernel_launch(void* const* d_in, const int* in_sizes, int n_in,
                              void* d_out, int out_size, void* d_ws, size_t ws_size,
                              hipStream_t stream) {
  const float* feat   = (const float*)d_in[0];
  const float* masker = (const float*)d_in[1];
  const float* tw     = (const float*)d_in[2];
  const float* tb     = (const float*)d_in[3];
  const float* lnw    = (const float*)d_in[4];
  const float* lnb    = (const float*)d_in[5];
  const float* gw     = (const float*)d_in[6];
  const float* gb     = (const float*)d_in[7];
  float* out = (float*)d_out;

  bf16_t* ws_attnT = (bf16_t*)d_ws;                  // 8192 bf16
  bf16_t* ws_WT    = ws_attnT + 2 * 64 * 64;         // 16384 bf16 (ends at byte 49152)
  float*  ws_U     = (float*)((char*)d_ws + 49152);  // 8192 f32
  float*  ws_const = (float*)((char*)d_ws + 81920);  // 2 f32

  prep_kernel<<<16, 256, 0, stream>>>(masker, lnw, lnb, tw, ws_attnT, ws_WT);
  prep2_kernel<<<1, 256, 0, stream>>>(tw, tb, gw, gb, ws_attnT, ws_U, ws_const);
  main_kernel<<<4096, 256, 0, stream>>>(feat, tb, ws_attnT, ws_WT, ws_U, ws_const, out);
}

// Round 5
// 206.709 us; speedup vs baseline: 2.0551x; 2.0551x over previous
//
#include <hip/hip_runtime.h>
#include <hip/hip_bf16.h>

#define NFEAT 50
#define LN_EPS 1e-5f
#define NEG_INF_C (-1000000000.0f)

typedef __bf16 bf16_t;
typedef __bf16 bf16x8 __attribute__((ext_vector_type(8)));
typedef __bf16 bf16x4 __attribute__((ext_vector_type(4)));
typedef float f32x4 __attribute__((ext_vector_type(4)));

// ws layout (all produced by prep kernels):
//   bf16[0]      attnT  [2][64][64]          attnT[t][g][f] = attn[t][f][g], zero-padded
//   bf16[8192]   WT     [4][64][64]          WT[t*2+i][e][k] = w0[t][i*64+k][e]
//   byte 49152   U_sw   [2][4][2][64][8] f32 gate matrix, A-frag-swizzled:
//                  U_sw[t][mm][kc][q*16+l16][j] = U[t][f=mm*16+l16][k=kc*32+q*8+j]
//   byte 81920   constv [2] f32              c_t = sum(tb_t*gw) + gb

__device__ inline float dot4(f32x4 a, f32x4 b) {
  return a[0]*b[0] + a[1]*b[1] + a[2]*b[2] + a[3]*b[3];
}

__global__ __launch_bounds__(256) void prep_kernel(
    const float* __restrict__ masker, const float* __restrict__ ln_w,
    const float* __restrict__ ln_b, const float* __restrict__ tw,
    bf16_t* __restrict__ ws_attnT, bf16_t* __restrict__ ws_WT)
{
  const int tid = threadIdx.x;
  const int lane = tid & 63;

  // ---- WT staging: 32 blocks x 256 threads x 2 elems = 16384 ----
  const int gidx = blockIdx.x * 256 + tid;
#pragma unroll
  for (int j = 0; j < 2; ++j) {
    int o = gidx * 2 + j;            // ((t*2+i)*64 + e)*64 + k
    int k = o & 63;
    int e = (o >> 6) & 63;
    int ti = o >> 12;                // t*2+i
    ws_WT[o] = (bf16_t)tw[(ti * 64 + k) * 64 + e];
  }

  // ---- attention columns: 128 tasks (t,g), one per wave ----
  const int col = blockIdx.x * 4 + (tid >> 6);  // 0..127
  const int f = lane;
  const bool fv = (f < NFEAT);
  const int t = col >> 6, g = col & 63;
  float val = 0.f;
  if (fv && g < NFEAT) {
    float a0 = masker[((t * 3 + 0) * NFEAT + f) * NFEAT + g];
    float a1 = masker[((t * 3 + 1) * NFEAT + f) * NFEAT + g];
    float a2 = masker[((t * 3 + 2) * NFEAT + f) * NFEAT + g];
    float prod = a0 * a1 * a2;
    val = prod > 0.f ? prod : 0.f;            // relu
  }
  float s = val;
  for (int off = 32; off > 0; off >>= 1) s += __shfl_xor(s, off);
  float mean = s / (float)NFEAT;
  float d = fv ? (val - mean) : 0.f;
  float v2 = d * d;
  for (int off = 32; off > 0; off >>= 1) v2 += __shfl_xor(v2, off);
  float var = v2 / (float)NFEAT;
  float lw = fv ? ln_w[f] : 0.f;
  float lb = fv ? ln_b[f] : 0.f;
  float aln = d * rsqrtf(var + LN_EPS) * lw + lb;
  float logit = aln + ((val != 0.f) ? 0.f : NEG_INF_C) + ((f == g) ? 1.f : 0.f);
  if (!fv) logit = -3.0e38f;
  float mx = logit;
  for (int off = 32; off > 0; off >>= 1) mx = fmaxf(mx, __shfl_xor(mx, off));
  float ex = fv ? expf(logit - mx) : 0.f;
  float se = ex;
  for (int off = 32; off > 0; off >>= 1) se += __shfl_xor(se, off);
  float attn = (fv && g < NFEAT && val != 0.f) ? (ex / se) : 0.f;
  ws_attnT[(t * 64 + g) * 64 + f] = (bf16_t)attn;
}

// Gate precompute, one wave per (t,f) pair: 128 waves over 32 blocks.
// U[t][f][k] = sum_e( W1_t[k,e]*gw[f,e] + W2_t[k,e]*v[t][f,e] ),
// v[t][f][e] = sum_{g<50} attn[t][f][g]*gw[g,e];  const_t = sum(tb_t*gw) + gb.
__global__ __launch_bounds__(256) void prep2_kernel(
    const float* __restrict__ tw, const float* __restrict__ tb,
    const float* __restrict__ gw, const float* __restrict__ gb,
    const bf16_t* __restrict__ ws_attnT, float* __restrict__ ws_U,
    float* __restrict__ ws_const)
{
  __shared__ float sv[4][2][64];   // per wave: [0]=v[e], [1]=gw[f,e]
  __shared__ float sred[8];
  const int tid = threadIdx.x;
  const int lane = tid & 63;
  const int w = tid >> 6;
  const int pair = blockIdx.x * 4 + w;   // 0..127
  const int t = pair >> 6;
  const int f = pair & 63;

  // ---- phase A: v[e], e = lane (coalesced gw, broadcast attnT) ----
  float v = 0.f;
  const bf16_t* at = ws_attnT + (t * 64) * 64 + f;   // attnT[t][g][f], stride 64
#pragma unroll 5
  for (int g = 0; g < NFEAT; ++g)
    v += (float)at[g * 64] * gw[g * 64 + lane];
  sv[w][0][lane] = v;
  sv[w][1][lane] = (f < NFEAT) ? gw[f * 64 + lane] : 0.f;
  // same-wave LDS write->read: in-order within a wave, no barrier needed

  // ---- phase B: U[k], k = lane ----
  float u = 0.f;
  if (f < NFEAT) {
    const f32x4* W1 = (const f32x4*)(tw + ((t * 2 + 0) * 64 + lane) * 64);
    const f32x4* W2 = (const f32x4*)(tw + ((t * 2 + 1) * 64 + lane) * 64);
    const f32x4* vp = (const f32x4*)sv[w][0];
    const f32x4* gp = (const f32x4*)sv[w][1];
#pragma unroll
    for (int e4 = 0; e4 < 16; ++e4)
      u += dot4(W1[e4], gp[e4]) + dot4(W2[e4], vp[e4]);
  }
  {
    const int k = lane;
    const int mm = f >> 4, l16r = f & 15, kc = k >> 5, q = (k >> 3) & 3, j = k & 7;
    ws_U[((((t * 4 + mm) * 2 + kc) * 64) + (q * 16 + l16r)) * 8 + j] = u;
  }

  // ---- const (block 0 only) ----
  if (blockIdx.x == 0) {
    float c0 = 0.f, c1 = 0.f;
    for (int i = tid; i < 3200; i += 256) {
      c0 += tb[i] * gw[i];
      c1 += tb[3200 + i] * gw[i];
    }
    for (int off = 32; off > 0; off >>= 1) { c0 += __shfl_xor(c0, off); c1 += __shfl_xor(c1, off); }
    if (lane == 0) { sred[w * 2] = c0; sred[w * 2 + 1] = c1; }
    __syncthreads();
    if (tid == 0) {
      float g = gb[0];
      ws_const[0] = sred[0] + sred[2] + sred[4] + sred[6] + g;
      ws_const[1] = sred[1] + sred[3] + sred[5] + sred[7] + g;
    }
  }
}

// Barrier-free main: wave = (b = blockIdx, e-slice = wave id). Each wave computes
// all 4 m-tiles for its 16 output columns; P round-trips through wave-private LDS
// (same-wave lgkmcnt only, NO __syncthreads); gate via precomputed U dot, in-wave.
__global__ __launch_bounds__(256) void main_kernel(
    const float* __restrict__ feat, const float* __restrict__ tb,
    const bf16_t* __restrict__ ws_attnT, const bf16_t* __restrict__ ws_WT,
    const float* __restrict__ ws_U, const float* __restrict__ ws_const,
    float* __restrict__ out)
{
  __shared__ bf16_t sP[4 * 2 * 16 * 72];   // [wave][t][16 e][72 f'-pitch]
  const int tid = threadIdx.x;
  const int w = tid >> 6;
  const int lane = tid & 63;
  const int l16 = lane & 15;
  const int quad = lane >> 4;
  const int e0 = w * 16;
  const int b = blockIdx.x;
  const float* featb = feat + b * (NFEAT * 64);

  // ---- F A-frags (fp32 -> bf16) + gate dot on the fly ----
  bf16x8 A[4][2];
  float g0 = 0.f, g1 = 0.f;
#pragma unroll
  for (int mm = 0; mm < 4; ++mm) {
    const int fr = mm * 16 + l16;
#pragma unroll
    for (int kc = 0; kc < 2; ++kc) {
      f32x4 x0 = {0.f, 0.f, 0.f, 0.f}, x1 = {0.f, 0.f, 0.f, 0.f};
      if (fr < NFEAT) {
        const f32x4* pa = (const f32x4*)(featb + fr * 64 + kc * 32 + quad * 8);
        x0 = pa[0]; x1 = pa[1];
      }
      const f32x4* u0 = (const f32x4*)(ws_U + ((((0 * 4 + mm) * 2 + kc) * 64) + lane) * 8);
      const f32x4* u1 = (const f32x4*)(ws_U + ((((1 * 4 + mm) * 2 + kc) * 64) + lane) * 8);
      g0 += dot4(x0, u0[0]) + dot4(x1, u0[1]);
      g1 += dot4(x0, u1[0]) + dot4(x1, u1[1]);
      bf16x8 a;
      a[0] = (bf16_t)x0[0]; a[1] = (bf16_t)x0[1]; a[2] = (bf16_t)x0[2]; a[3] = (bf16_t)x0[3];
      a[4] = (bf16_t)x1[0]; a[5] = (bf16_t)x1[1]; a[6] = (bf16_t)x1[2]; a[7] = (bf16_t)x1[3];
      A[mm][kc] = a;
    }
  }
#pragma unroll
  for (int off = 32; off > 0; off >>= 1) {
    g0 += __shfl_xor(g0, off);
    g1 += __shfl_xor(g1, off);
  }
  g0 += ws_const[0]; g1 += ws_const[1];
  const float mx = fmaxf(g0, g1);
  const float ex0 = expf(g0 - mx), ex1 = expf(g1 - mx);
  const float inv = 1.f / (ex0 + ex1);
  const float ga0 = ex0 * inv, ga1 = ex1 * inv;

  f32x4 H[2][4];
#pragma unroll
  for (int t = 0; t < 2; ++t) {
    // ---- P = F @ W2_t (this wave's e-slice, all f' rows) ----
    f32x4 P[4];
#pragma unroll
    for (int mm = 0; mm < 4; ++mm) P[mm] = (f32x4){0.f, 0.f, 0.f, 0.f};
#pragma unroll
    for (int kc = 0; kc < 2; ++kc) {
      const bf16x8 bw2 = *(const bf16x8*)(ws_WT + ((t * 2 + 1) * 64 + e0 + l16) * 64 + kc * 32 + quad * 8);
#pragma unroll
      for (int mm = 0; mm < 4; ++mm)
        P[mm] = __builtin_amdgcn_mfma_f32_16x16x32_bf16(A[mm][kc], bw2, P[mm], 0, 0, 0);
    }
    // ---- wave-private LDS transpose: sP[e][f'] (no barrier, same-wave lgkmcnt) ----
    bf16_t* sp = sP + (w * 2 + t) * (16 * 72);
#pragma unroll
    for (int mm = 0; mm < 4; ++mm) {
      bf16x4 pv;
      pv[0] = (bf16_t)P[mm][0]; pv[1] = (bf16_t)P[mm][1];
      pv[2] = (bf16_t)P[mm][2]; pv[3] = (bf16_t)P[mm][3];
      *(bf16x4*)(sp + l16 * 72 + mm * 16 + quad * 4) = pv;
    }
    // ---- H_t = F@W1_t + attnT_t@P ----
#pragma unroll
    for (int mm = 0; mm < 4; ++mm) H[t][mm] = (f32x4){0.f, 0.f, 0.f, 0.f};
#pragma unroll
    for (int kc = 0; kc < 2; ++kc) {
      const bf16x8 bw1 = *(const bf16x8*)(ws_WT + ((t * 2 + 0) * 64 + e0 + l16) * 64 + kc * 32 + quad * 8);
#pragma unroll
      for (int mm = 0; mm < 4; ++mm)
        H[t][mm] = __builtin_amdgcn_mfma_f32_16x16x32_bf16(A[mm][kc], bw1, H[t][mm], 0, 0, 0);
    }
#pragma unroll
    for (int kc = 0; kc < 2; ++kc) {
      const bf16x8 bp = *(const bf16x8*)(sp + l16 * 72 + kc * 32 + quad * 8);
#pragma unroll
      for (int mm = 0; mm < 4; ++mm) {
        const bf16x8 ac = *(const bf16x8*)(ws_attnT + (t * 64 + mm * 16 + l16) * 64 + kc * 32 + quad * 8);
        H[t][mm] = __builtin_amdgcn_mfma_f32_16x16x32_bf16(ac, bp, H[t][mm], 0, 0, 0);
      }
    }
  }

  // ---- epilogue: +tb, gate-weighted sum, store ----
  float* outb = out + b * (NFEAT * 64);
#pragma unroll
  for (int mm = 0; mm < 4; ++mm) {
#pragma unroll
    for (int r = 0; r < 4; ++r) {
      const int f = mm * 16 + quad * 4 + r;
      if (f < NFEAT) {
        const int o = f * 64 + e0 + l16;
        outb[o] = ga0 * (H[0][mm][r] + tb[o]) + ga1 * (H[1][mm][r] + tb[3200 + o]);
      }
    }
  }
}

extern "C" void kernel_launch(void* const* d_in, const int* in_sizes, int n_in,
                              void* d_out, int out_size, void* d_ws, size_t ws_size,
                              hipStream_t stream) {
  const float* feat   = (const float*)d_in[0];
  const float* masker = (const float*)d_in[1];
  const float* tw     = (const float*)d_in[2];
  const float* tb     = (const float*)d_in[3];
  const float* lnw    = (const float*)d_in[4];
  const float* lnb    = (const float*)d_in[5];
  const float* gw     = (const float*)d_in[6];
  const float* gb     = (const float*)d_in[7];
  float* out = (float*)d_out;

  bf16_t* ws_attnT = (bf16_t*)d_ws;                  // 8192 bf16
  bf16_t* ws_WT    = ws_attnT + 2 * 64 * 64;         // 16384 bf16 (ends at byte 49152)
  float*  ws_U     = (float*)((char*)d_ws + 49152);  // 8192 f32
  float*  ws_const = (float*)((char*)d_ws + 81920);  // 2 f32

  prep_kernel<<<32, 256, 0, stream>>>(masker, lnw, lnb, tw, ws_attnT, ws_WT);
  prep2_kernel<<<32, 256, 0, stream>>>(tw, tb, gw, gb, ws_attnT, ws_U, ws_const);
  main_kernel<<<4096, 256, 0, stream>>>(feat, tb, ws_attnT, ws_WT, ws_U, ws_const, out);
}